// Round 8
// baseline (109.519 us; speedup 1.0000x reference)
//
#include <hip/hip_runtime.h>

// Causal attention, fp32 in/out, B=8 S=2048 D=64, NO 1/sqrt(d) scaling.
// R23 = INSTRUMENTED PROBE of R22/R19 (deliberate one-round regression):
//  - R22 post-mortem: cvt_pk P-conversion exactly neutral (90.273 vs
//    90.274) -> VALU-count theory dead. Refuted so far: occupancy
//    (R17/R19), load volume (R20/R21), VALU ops (R22). Only load SHAPE
//    (R18) ever paid. All post-R18 attn counters are INFERRED - the
//    kernel hides below the five ~42us ws-poison fills in top-5.
//  - R23: run the attn main loop TWICE per block (#pragma unroll 1 rep
//    loop; rep0 kept alive via asm volatile per learn_hip rule #17, then
//    re-init; rep1 output identical -> absmax stays exactly 0.03125).
//    (1) dur(probe) - 90.27 = T_attn exactly (differential, no ledger).
//    (2) attn_main doubles to ~2*T_attn > 42us -> surfaces in top-5 WITH
//        counters (VALUBusy/MfmaUtil/Occupancy/FETCH/VGPR).
//  - Pre-committed: VALUBusy>50% -> attack softmax structure; MfmaUtil>40%
//    -> reduce MFMA count; both low + occ ~38% -> cross-chunk prefetch;
//    occ low -> residency wrong. R24 reverts the rep loop + applies fix.
// Ledger: ~42us fill + ~6us prep + ~14us launch/misc fixed (to be
// re-derived from this probe).
// Fragment layouts (verified R2):
//   A[m][k]: m=lane&15, k=quad*8+j | B[k][n]: n=lane&15, k=quad*8+j
//   C/D:     col=lane&15, row=quad*4+reg
// Vf layout: chunk c(32 keys), dim-group nt: lane l holds
//   V[b][c*32+(l>>4)*8+j][nt*16+(l&15)], j=0..7 (16B, consecutive by lane).
// Kf layout: subtile S(16 keys), frag f: lane l holds 16B at
//   Kf + (b*128+S)*2048 + f*512 + l*8   (elements, 2B each)
//   f0/f1 = hi dims 0-31 / 32-63, f2/f3 = lo dims 0-31 / 32-63.

#define BATCH 8
#define SEQ 2048
#define DIM 64
#define NEL (BATCH * SEQ * DIM)

typedef __attribute__((ext_vector_type(8))) short short8;
typedef __attribute__((ext_vector_type(4))) float f32x4;

#define MFMA(a, b, c) __builtin_amdgcn_mfma_f32_16x16x32_bf16(a, b, c, 0, 0, 0)

__device__ __forceinline__ unsigned short f2bf(float x) {   // RNE
    unsigned u = __float_as_uint(x);
    unsigned r = u + 0x7fffu + ((u >> 16) & 1u);
    return (unsigned short)(r >> 16);
}
__device__ __forceinline__ float bf2f(unsigned short h) {
    return __uint_as_float(((unsigned)h) << 16);
}
// packed f32x2 -> bf16x2, RNE; lo 16 bits from a, hi 16 bits from b.
__device__ __forceinline__ unsigned cvt_pk_bf16(float a, float b) {
    unsigned r;
    asm("v_cvt_pk_bf16_f32 %0, %1, %2" : "=v"(r) : "v"(a), "v"(b));
    return r;
}
__device__ __forceinline__ short8 ld8(const unsigned short* p) {
    return *(const short8*)p;
}
// truncation hi/lo split (R14-verified): hi = upper16(x); lo = trunc16(x-hi).
__device__ __forceinline__ void splitA(float4 a, float4 b, short8& h8, short8& l8) {
    float v[8] = {a.x, a.y, a.z, a.w, b.x, b.y, b.z, b.w};
#pragma unroll
    for (int i = 0; i < 8; ++i) {
        unsigned u  = __float_as_uint(v[i]);
        unsigned hu = u & 0xffff0000u;
        h8[i] = (short)(hu >> 16);
        float lf = v[i] - __uint_as_float(hu);
        l8[i] = (short)(__float_as_uint(lf) >> 16);
    }
}

__device__ __forceinline__ float dpp_max16(float x) {
    float o;
    o = __int_as_float(__builtin_amdgcn_update_dpp(0, __float_as_int(x), 0xB1, 0xF, 0xF, true));
    x = fmaxf(x, o);
    o = __int_as_float(__builtin_amdgcn_update_dpp(0, __float_as_int(x), 0x4E, 0xF, 0xF, true));
    x = fmaxf(x, o);
    o = __int_as_float(__builtin_amdgcn_update_dpp(0, __float_as_int(x), 0x141, 0xF, 0xF, true));
    x = fmaxf(x, o);
    o = __int_as_float(__builtin_amdgcn_update_dpp(0, __float_as_int(x), 0x140, 0xF, 0xF, true));
    return fmaxf(x, o);
}
__device__ __forceinline__ float dpp_sum16(float x) {
    float o;
    o = __int_as_float(__builtin_amdgcn_update_dpp(0, __float_as_int(x), 0xB1, 0xF, 0xF, true));
    x += o;
    o = __int_as_float(__builtin_amdgcn_update_dpp(0, __float_as_int(x), 0x4E, 0xF, 0xF, true));
    x += o;
    o = __int_as_float(__builtin_amdgcn_update_dpp(0, __float_as_int(x), 0x141, 0xF, 0xF, true));
    x += o;
    o = __int_as_float(__builtin_amdgcn_update_dpp(0, __float_as_int(x), 0x140, 0xF, 0xF, true));
    return x + o;
}

// ---- pre-pass: K fragment-major hi/lo (blk<512) + V fragment-major ----
__global__ __launch_bounds__(256) void prep(
    const float* __restrict__ K, const float* __restrict__ V,
    unsigned short* __restrict__ Kf, unsigned short* __restrict__ Vf)
{
    __shared__ unsigned short sT[64][72];   // [dim][key] for one 64-key tile
    const int blk = blockIdx.x;
    const int t = threadIdx.x;

    if (blk < 512) {
        // one thread = one (subtile, dim-half, lane) chunk: 8 fp32 -> hi8+lo8
        const int g  = blk * 256 + t;       // 0..131071
        const int l  = g & 63;
        const int h  = (g >> 6) & 1;
        const int Sg = g >> 7;              // b*128 + S, 0..1023
        const int b  = Sg >> 7;
        const int S  = Sg & 127;
        const int key = S * 16 + (l & 15);
        const float* src = K + ((size_t)(b * SEQ + key)) * DIM + h * 32 + (l >> 4) * 8;
        float4 a = *(const float4*)src;
        float4 c = *(const float4*)(src + 4);
        float v[8] = {a.x, a.y, a.z, a.w, c.x, c.y, c.z, c.w};
        short8 h8, l8;
#pragma unroll
        for (int i = 0; i < 8; ++i) {
            unsigned short hh = f2bf(v[i]);
            h8[i] = (short)hh;
            l8[i] = (short)f2bf(v[i] - bf2f(hh));
        }
        unsigned short* dst = Kf + (((size_t)Sg) << 11) + (h << 9) + l * 8;
        *(short8*)dst = h8;                  // frag f = h   (hi)
        *(short8*)(dst + 1024) = l8;         // frag f = 2+h (lo)
        return;
    }

    const int tile = blk - 512;             // 8 batches * 32 tiles of 64 keys
    const int b = tile >> 5;
    const int s0 = (tile & 31) * 64;
    const int srow = t >> 4;
    const int d4   = (t & 15) * 4;
#pragma unroll
    for (int i = 0; i < 4; ++i) {
        const int row = srow + i * 16;
        float4 v = *(const float4*)(V + ((size_t)(b * SEQ + s0 + row)) * DIM + d4);
        sT[d4 + 0][row] = f2bf(v.x);
        sT[d4 + 1][row] = f2bf(v.y);
        sT[d4 + 2][row] = f2bf(v.z);
        sT[d4 + 3][row] = f2bf(v.w);
    }
    __syncthreads();
#pragma unroll
    for (int i = 0; i < 2; ++i) {
        const int fid = t + i * 256;
        const int cc  = fid >> 8;
        const int nt  = (fid >> 6) & 3;
        const int l   = fid & 63;
        const int key = cc * 32 + (l >> 4) * 8;
        const int dim = nt * 16 + (l & 15);
        const int c   = (s0 >> 5) + cc;
        unsigned short* dst =
            Vf + ((((size_t)(b * 64 + c)) * 4 + nt) << 9) + l * 8;
        *(float4*)dst = *(const float4*)&sT[dim][key];
    }
}

// ---- main: 1024 blocks x 256 threads (4 waves), ONE q-tile per block ----
// PROBE: main loop executed twice (rep loop); rep1 output == rep0 output.
__global__ __launch_bounds__(256) void attn_main(
    const float* __restrict__ Q,
    const unsigned short* __restrict__ Kf,
    const unsigned short* __restrict__ Vf, float* __restrict__ O)
{
    // per-wave union scratch: sP (ushort[16][136]) == sO (float[16][68]) = 4352B
    __shared__ __align__(16) char scratch[4][4352];
    __shared__ float sMl[4][16][2];

    const int bid  = blockIdx.x;
    // snake mapping: per-CU work sum constant under striped assignment
    const int g    = bid >> 8;              // grid quarter 0..3
    const int idx  = bid & 255;
    const int b    = idx & (BATCH - 1);
    const int tl   = idx >> 3;              // 0..31
    const int qt   = (g & 1) ? (g * 32 + 31 - tl) : (g * 32 + tl);

    const int t    = threadIdx.x;
    const int w    = t >> 6;
    const int lane = t & 63;
    const int quad = lane >> 4;
    const int n16  = lane & 15;
    const int boff = b * SEQ;

    unsigned short* sPw = (unsigned short*)scratch[w];   // [16][136]
    float*          sOw = (float*)scratch[w];            // [16][68]

    // base of this batch's Kf region, plus this lane's 16B slot
    const unsigned short* KfL = Kf + (((size_t)(b * 128)) << 11) + lane * 8;

    const int q0 = qt * 16;
    const int q_max = q0 + 15;

    // ---- Q fragments: inline fp32 -> hi/lo truncation split ----
    short8 qh0, ql0, qh1, ql1;
    {
        const float* qb = Q + ((size_t)(boff + q0 + n16)) * DIM + quad * 8;
        splitA(*(const float4*)(qb),      *(const float4*)(qb + 4),  qh0, ql0);
        splitA(*(const float4*)(qb + 32), *(const float4*)(qb + 36), qh1, ql1);
    }

    float m0, m1, m2, m3;
    float l0, l1, l2, l3;
    f32x4 oacc[4];

    // ---- PROBE rep loop: unroll 1 prevents cross-rep CSE; keep-alive
    //      asm prevents DCE of rep0 (learn_hip rule #17). rep1 == rep0. ----
#pragma unroll 1
    for (int rep = 0; rep < 2; ++rep) {
        m0 = -1e30f; m1 = -1e30f; m2 = -1e30f; m3 = -1e30f;
        l0 = 0.f; l1 = 0.f; l2 = 0.f; l3 = 0.f;
#pragma unroll
        for (int i = 0; i < 4; ++i) oacc[i] = (f32x4){0.f, 0.f, 0.f, 0.f};

        for (int kb = w * 128; kb <= q_max; kb += 512) {
            const int rem  = q_max - kb;
            const int nsub = min(8, (rem >> 4) + 1);
            const int nchain = (nsub + 1) >> 1;
            f32x4 sacc[8];

            // ---- QK^T: 8 subtiles in pairs; contiguous 1KB frag loads ----
#pragma unroll
            for (int gp = 0; gp < 4; ++gp) {
                const int stA = 2 * gp, stB = stA + 1;
                if (stA < nsub) {
                    const unsigned short* pA = KfL + (((size_t)((kb >> 4) + stA)) << 11);
                    short8 khA0 = ld8(pA),        khA1 = ld8(pA + 512);
                    short8 klA0 = ld8(pA + 1024), klA1 = ld8(pA + 1536);
                    const bool okB = (stB < nsub);
                    const unsigned short* pB = KfL + (((size_t)((kb >> 4) + stB)) << 11);
                    short8 khB0, khB1, klB0, klB1;
                    if (okB) {
                        khB0 = ld8(pB);        khB1 = ld8(pB + 512);
                        klB0 = ld8(pB + 1024); klB1 = ld8(pB + 1536);
                    }
                    f32x4 accA = (f32x4){0.f, 0.f, 0.f, 0.f};
                    accA = MFMA(qh0, khA0, accA);
                    accA = MFMA(qh1, khA1, accA);
                    accA = MFMA(qh0, klA0, accA);
                    accA = MFMA(qh1, klA1, accA);
                    accA = MFMA(ql0, khA0, accA);
                    accA = MFMA(ql1, khA1, accA);
                    sacc[stA] = accA;
                    if (okB) {
                        f32x4 accB = (f32x4){0.f, 0.f, 0.f, 0.f};
                        accB = MFMA(qh0, khB0, accB);
                        accB = MFMA(qh1, khB1, accB);
                        accB = MFMA(qh0, klB0, accB);
                        accB = MFMA(qh1, klB1, accB);
                        accB = MFMA(ql0, khB0, accB);
                        accB = MFMA(ql1, khB1, accB);
                        sacc[stB] = accB;
                    } else {
                        sacc[stB] = (f32x4){-1e30f, -1e30f, -1e30f, -1e30f};
                    }
                } else {
                    sacc[stA] = (f32x4){-1e30f, -1e30f, -1e30f, -1e30f};
                    sacc[stB] = (f32x4){-1e30f, -1e30f, -1e30f, -1e30f};
                }
            }

            // ---- causal mask: any chunk overlapping any query row ----
            if (kb + 127 > q0) {
#pragma unroll
                for (int st = 0; st < 8; ++st) {
                    if (st < nsub) {
                        const int key = kb + st * 16 + n16;
#pragma unroll
                        for (int r = 0; r < 4; ++r)
                            if (key > q0 + quad * 4 + r) sacc[st][r] = -1e30f;
                    }
                }
            }

            // ---- online softmax over 128 keys (DPP reductions) ----
            float mt0 = sacc[0][0], mt1 = sacc[0][1], mt2 = sacc[0][2], mt3 = sacc[0][3];
#pragma unroll
            for (int st = 1; st < 8; ++st) {
                mt0 = fmaxf(mt0, sacc[st][0]);
                mt1 = fmaxf(mt1, sacc[st][1]);
                mt2 = fmaxf(mt2, sacc[st][2]);
                mt3 = fmaxf(mt3, sacc[st][3]);
            }
            mt0 = dpp_max16(mt0); mt1 = dpp_max16(mt1);
            mt2 = dpp_max16(mt2); mt3 = dpp_max16(mt3);
            const float mn0 = fmaxf(m0, mt0), mn1 = fmaxf(m1, mt1);
            const float mn2 = fmaxf(m2, mt2), mn3 = fmaxf(m3, mt3);
            const float a0 = __expf(m0 - mn0), a1 = __expf(m1 - mn1);
            const float a2 = __expf(m2 - mn2), a3 = __expf(m3 - mn3);
            m0 = mn0; m1 = mn1; m2 = mn2; m3 = mn3;

            float ps0 = 0.f, ps1 = 0.f, ps2 = 0.f, ps3 = 0.f;
            const int stmax = 2 * nchain;
#pragma unroll
            for (int st = 0; st < 8; ++st) {
                if (st < stmax) {
                    float p0 = 0.f, p1 = 0.f, p2 = 0.f, p3 = 0.f;
                    if (st < nsub) {
                        p0 = __expf(sacc[st][0] - mn0);
                        p1 = __expf(sacc[st][1] - mn1);
                        p2 = __expf(sacc[st][2] - mn2);
                        p3 = __expf(sacc[st][3] - mn3);
                        ps0 += p0; ps1 += p1; ps2 += p2; ps3 += p3;
                    }
                    const int col = st * 16 + n16;
                    // packed RNE convert (R22, neutral but fewer ops)
                    const unsigned r01 = cvt_pk_bf16(p0, p1);
                    const unsigned r23 = cvt_pk_bf16(p2, p3);
                    sPw[(quad * 4 + 0) * 136 + col] = (unsigned short)r01;
                    sPw[(quad * 4 + 1) * 136 + col] = (unsigned short)(r01 >> 16);
                    sPw[(quad * 4 + 2) * 136 + col] = (unsigned short)r23;
                    sPw[(quad * 4 + 3) * 136 + col] = (unsigned short)(r23 >> 16);
                }
            }
            ps0 = dpp_sum16(ps0); ps1 = dpp_sum16(ps1);
            ps2 = dpp_sum16(ps2); ps3 = dpp_sum16(ps3);
            l0 = l0 * a0 + ps0; l1 = l1 * a1 + ps1;
            l2 = l2 * a2 + ps2; l3 = l3 * a3 + ps3;
#pragma unroll
            for (int nt = 0; nt < 4; ++nt) {
                oacc[nt][0] *= a0; oacc[nt][1] *= a1;
                oacc[nt][2] *= a2; oacc[nt][3] *= a3;
            }

            // ---- PV: P from same-wave LDS; V via dense fragment-major loads ----
#pragma unroll
            for (int ch = 0; ch < 4; ++ch) {
                if (ch < nchain) {
                    short8 pa = ld8(&sPw[n16 * 136 + ch * 32 + quad * 8]);
                    const size_t cbase =
                        (((size_t)(b * 64 + (kb >> 5) + ch)) * 4) << 9;
#pragma unroll
                    for (int nt = 0; nt < 4; ++nt) {
                        short8 vv = ld8(Vf + cbase + (nt << 9) + lane * 8);
                        oacc[nt] = MFMA(pa, vv, oacc[nt]);
                    }
                }
            }
        }

        // keep rep0's results live so the whole pass can't be DCE'd
        asm volatile("" ::
            "v"(oacc[0][0]), "v"(oacc[1][1]), "v"(oacc[2][2]), "v"(oacc[3][3]),
            "v"(l0), "v"(l1), "v"(l2), "v"(l3),
            "v"(m0), "v"(m1), "v"(m2), "v"(m3));
    }

    // ---- flash-combine the 4 waves' partials (sO overlays sP) ----
#pragma unroll
    for (int nt = 0; nt < 4; ++nt)
#pragma unroll
        for (int r = 0; r < 4; ++r)
            sOw[(quad * 4 + r) * 68 + nt * 16 + n16] = oacc[nt][r];
    if (n16 == 0) {
        sMl[w][quad * 4 + 0][0] = m0; sMl[w][quad * 4 + 0][1] = l0;
        sMl[w][quad * 4 + 1][0] = m1; sMl[w][quad * 4 + 1][1] = l1;
        sMl[w][quad * 4 + 2][0] = m2; sMl[w][quad * 4 + 2][1] = l2;
        sMl[w][quad * 4 + 3][0] = m3; sMl[w][quad * 4 + 3][1] = l3;
    }
    __syncthreads();

    const int row  = t >> 4;
    const int col4 = (t & 15) * 4;
    float M = fmaxf(fmaxf(sMl[0][row][0], sMl[1][row][0]),
                    fmaxf(sMl[2][row][0], sMl[3][row][0]));
    float L = 0.f;
    float ox = 0.f, oy = 0.f, oz = 0.f, ow = 0.f;
#pragma unroll
    for (int wv = 0; wv < 4; ++wv) {
        const float ew = __expf(sMl[wv][row][0] - M);
        L += ew * sMl[wv][row][1];
        const float* op = (const float*)scratch[wv] + row * 68 + col4;
        ox += ew * op[0]; oy += ew * op[1]; oz += ew * op[2]; ow += ew * op[3];
    }
    const float inv = 1.0f / L;
    float4 res = make_float4(ox * inv, oy * inv, oz * inv, ow * inv);
    *(float4*)(O + ((size_t)(boff + q0 + row)) * DIM + col4) = res;
}

extern "C" void kernel_launch(void* const* d_in, const int* in_sizes, int n_in,
                              void* d_out, int out_size, void* d_ws, size_t ws_size,
                              hipStream_t stream) {
    const float* q = (const float*)d_in[0];
    const float* k = (const float*)d_in[1];
    const float* v = (const float*)d_in[2];
    float* out = (float*)d_out;

    unsigned short* Kf = (unsigned short*)d_ws;   // 4 MB fragment-major hi/lo
    unsigned short* Vf = Kf + 2 * NEL;            // 2 MB fragment-major V

    prep<<<dim3(512 + 256), dim3(256), 0, stream>>>(k, v, Kf, Vf);
    attn_main<<<dim3(1024), dim3(256), 0, stream>>>(q, Kf, Vf, out);
}

// Round 9
// 98.684 us; speedup vs baseline: 1.1098x; 1.1098x over previous
//
#include <hip/hip_runtime.h>

// Causal attention, fp32 in/out, B=8 S=2048 D=64, NO 1/sqrt(d) scaling.
// R24 = UNIFORM-WORK 2D DECOMPOSITION (tail kill), from the R23 probe:
//  - R23 probe: attn_main = 37us, K-loop only 19us, Occupancy 21% with a
//    grid that is fully resident at t=0 (1024 blocks = 4/CU, NO refill).
//    Triangular per-block work -> endgame = each CU runs its longest block
//    ALONE, latency-exposed serial chain x4 iterations (~18us of tail).
//    Explains every null: occupancy (R17/R19), load volume (R20/R21),
//    VALU count (R22) - none shorten a serial chain; only per-load
//    latency (R18) did.
//  - R24: grid = (b, qt, seg) with 512-key segments, nseg(qt)=qt/32+1
//    -> 2560 near-uniform blocks, each wave <=1 chunk-iteration (critical
//    path = ONE chain). 10 blocks/CU with 4 resident -> continuous
//    backfill. Blocks write unnormalized partials (M,L,O) to ws; combine
//    kernel (1024 blocks) merges <=4 segments + normalizes. Dispatch
//    boundary guarantees cross-XCD visibility.
//  - Numerics: within-segment math identical; only the final combine is
//    re-associated (f32 reorder, bf16-dominated) -> absmax expect 0.03125.
//  - Pre-committed: if total doesn't drop >=4us, tail theory dead ->
//    balanced-throughput floor reached -> declare roofline.
// Ledger (R23-corrected): 42us fill + ~6us prep + 37us attn + ~5 misc = 90.
// Fragment layouts (verified R2):
//   A[m][k]: m=lane&15, k=quad*8+j | B[k][n]: n=lane&15, k=quad*8+j
//   C/D:     col=lane&15, row=quad*4+reg
// Vf layout: chunk c(32 keys), dim-group nt: lane l holds
//   V[b][c*32+(l>>4)*8+j][nt*16+(l&15)], j=0..7 (16B, consecutive by lane).
// Kf layout: subtile S(16 keys), frag f: lane l holds 16B at
//   Kf + (b*128+S)*2048 + f*512 + l*8   (elements, 2B each)
//   f0/f1 = hi dims 0-31 / 32-63, f2/f3 = lo dims 0-31 / 32-63.
// Partial layout: slot pb=(b*128+qt)*4+seg:
//   Po[pb][16][64] f32 (unnormalized), Pml[pb][16][2] f32 (M,L).

#define BATCH 8
#define SEQ 2048
#define DIM 64
#define NEL (BATCH * SEQ * DIM)

typedef __attribute__((ext_vector_type(8))) short short8;
typedef __attribute__((ext_vector_type(4))) float f32x4;

#define MFMA(a, b, c) __builtin_amdgcn_mfma_f32_16x16x32_bf16(a, b, c, 0, 0, 0)

__device__ __forceinline__ unsigned short f2bf(float x) {   // RNE
    unsigned u = __float_as_uint(x);
    unsigned r = u + 0x7fffu + ((u >> 16) & 1u);
    return (unsigned short)(r >> 16);
}
__device__ __forceinline__ float bf2f(unsigned short h) {
    return __uint_as_float(((unsigned)h) << 16);
}
// packed f32x2 -> bf16x2, RNE; lo 16 bits from a, hi 16 bits from b.
__device__ __forceinline__ unsigned cvt_pk_bf16(float a, float b) {
    unsigned r;
    asm("v_cvt_pk_bf16_f32 %0, %1, %2" : "=v"(r) : "v"(a), "v"(b));
    return r;
}
__device__ __forceinline__ short8 ld8(const unsigned short* p) {
    return *(const short8*)p;
}
// truncation hi/lo split (R14-verified): hi = upper16(x); lo = trunc16(x-hi).
__device__ __forceinline__ void splitA(float4 a, float4 b, short8& h8, short8& l8) {
    float v[8] = {a.x, a.y, a.z, a.w, b.x, b.y, b.z, b.w};
#pragma unroll
    for (int i = 0; i < 8; ++i) {
        unsigned u  = __float_as_uint(v[i]);
        unsigned hu = u & 0xffff0000u;
        h8[i] = (short)(hu >> 16);
        float lf = v[i] - __uint_as_float(hu);
        l8[i] = (short)(__float_as_uint(lf) >> 16);
    }
}

__device__ __forceinline__ float dpp_max16(float x) {
    float o;
    o = __int_as_float(__builtin_amdgcn_update_dpp(0, __float_as_int(x), 0xB1, 0xF, 0xF, true));
    x = fmaxf(x, o);
    o = __int_as_float(__builtin_amdgcn_update_dpp(0, __float_as_int(x), 0x4E, 0xF, 0xF, true));
    x = fmaxf(x, o);
    o = __int_as_float(__builtin_amdgcn_update_dpp(0, __float_as_int(x), 0x141, 0xF, 0xF, true));
    x = fmaxf(x, o);
    o = __int_as_float(__builtin_amdgcn_update_dpp(0, __float_as_int(x), 0x140, 0xF, 0xF, true));
    return fmaxf(x, o);
}
__device__ __forceinline__ float dpp_sum16(float x) {
    float o;
    o = __int_as_float(__builtin_amdgcn_update_dpp(0, __float_as_int(x), 0xB1, 0xF, 0xF, true));
    x += o;
    o = __int_as_float(__builtin_amdgcn_update_dpp(0, __float_as_int(x), 0x4E, 0xF, 0xF, true));
    x += o;
    o = __int_as_float(__builtin_amdgcn_update_dpp(0, __float_as_int(x), 0x141, 0xF, 0xF, true));
    x += o;
    o = __int_as_float(__builtin_amdgcn_update_dpp(0, __float_as_int(x), 0x140, 0xF, 0xF, true));
    return x + o;
}

// ---- pre-pass: K fragment-major hi/lo (blk<512) + V fragment-major ----
__global__ __launch_bounds__(256) void prep(
    const float* __restrict__ K, const float* __restrict__ V,
    unsigned short* __restrict__ Kf, unsigned short* __restrict__ Vf)
{
    __shared__ unsigned short sT[64][72];   // [dim][key] for one 64-key tile
    const int blk = blockIdx.x;
    const int t = threadIdx.x;

    if (blk < 512) {
        // one thread = one (subtile, dim-half, lane) chunk: 8 fp32 -> hi8+lo8
        const int g  = blk * 256 + t;       // 0..131071
        const int l  = g & 63;
        const int h  = (g >> 6) & 1;
        const int Sg = g >> 7;              // b*128 + S, 0..1023
        const int b  = Sg >> 7;
        const int S  = Sg & 127;
        const int key = S * 16 + (l & 15);
        const float* src = K + ((size_t)(b * SEQ + key)) * DIM + h * 32 + (l >> 4) * 8;
        float4 a = *(const float4*)src;
        float4 c = *(const float4*)(src + 4);
        float v[8] = {a.x, a.y, a.z, a.w, c.x, c.y, c.z, c.w};
        short8 h8, l8;
#pragma unroll
        for (int i = 0; i < 8; ++i) {
            unsigned short hh = f2bf(v[i]);
            h8[i] = (short)hh;
            l8[i] = (short)f2bf(v[i] - bf2f(hh));
        }
        unsigned short* dst = Kf + (((size_t)Sg) << 11) + (h << 9) + l * 8;
        *(short8*)dst = h8;                  // frag f = h   (hi)
        *(short8*)(dst + 1024) = l8;         // frag f = 2+h (lo)
        return;
    }

    const int tile = blk - 512;             // 8 batches * 32 tiles of 64 keys
    const int b = tile >> 5;
    const int s0 = (tile & 31) * 64;
    const int srow = t >> 4;
    const int d4   = (t & 15) * 4;
#pragma unroll
    for (int i = 0; i < 4; ++i) {
        const int row = srow + i * 16;
        float4 v = *(const float4*)(V + ((size_t)(b * SEQ + s0 + row)) * DIM + d4);
        sT[d4 + 0][row] = f2bf(v.x);
        sT[d4 + 1][row] = f2bf(v.y);
        sT[d4 + 2][row] = f2bf(v.z);
        sT[d4 + 3][row] = f2bf(v.w);
    }
    __syncthreads();
#pragma unroll
    for (int i = 0; i < 2; ++i) {
        const int fid = t + i * 256;
        const int cc  = fid >> 8;
        const int nt  = (fid >> 6) & 3;
        const int l   = fid & 63;
        const int key = cc * 32 + (l >> 4) * 8;
        const int dim = nt * 16 + (l & 15);
        const int c   = (s0 >> 5) + cc;
        unsigned short* dst =
            Vf + ((((size_t)(b * 64 + c)) * 4 + nt) << 9) + l * 8;
        *(float4*)dst = *(const float4*)&sT[dim][key];
    }
}

// ---- main: 2560 uniform blocks x 256 threads; one 512-key segment each ----
__global__ __launch_bounds__(256) void attn_main(
    const float* __restrict__ Q,
    const unsigned short* __restrict__ Kf,
    const unsigned short* __restrict__ Vf,
    float* __restrict__ Po, float* __restrict__ Pml)
{
    // per-wave union scratch: sP (ushort[16][136]) == sO (float[16][68]) = 4352B
    __shared__ __align__(16) char scratch[4][4352];
    __shared__ float sMl[4][16][2];

    // ---- block -> (b, qt, seg): seg groups 32 tiles x (g+1) segments ----
    const int fid  = blockIdx.x;            // 0..2559
    const int b    = fid & (BATCH - 1);
    const int rest = fid >> 3;              // 0..319
    int qt, seg;
    if (rest < 32)       { qt = rest;                          seg = 0; }
    else if (rest < 96)  { int o = rest - 32;  qt = 32 + (o >> 1); seg = o & 1; }
    else if (rest < 192) { int o = rest - 96;  int q3 = o / 3; qt = 64 + q3; seg = o - q3 * 3; }
    else                 { int o = rest - 192; qt = 96 + (o >> 2); seg = o & 3; }

    const int t    = threadIdx.x;
    const int w    = t >> 6;
    const int lane = t & 63;
    const int quad = lane >> 4;
    const int n16  = lane & 15;
    const int boff = b * SEQ;

    unsigned short* sPw = (unsigned short*)scratch[w];   // [16][136]
    float*          sOw = (float*)scratch[w];            // [16][68]

    const unsigned short* KfL = Kf + (((size_t)(b * 128)) << 11) + lane * 8;

    const int q0 = qt * 16;
    const int q_max = q0 + 15;

    // ---- Q fragments: inline fp32 -> hi/lo truncation split ----
    short8 qh0, ql0, qh1, ql1;
    {
        const float* qb = Q + ((size_t)(boff + q0 + n16)) * DIM + quad * 8;
        splitA(*(const float4*)(qb),      *(const float4*)(qb + 4),  qh0, ql0);
        splitA(*(const float4*)(qb + 32), *(const float4*)(qb + 36), qh1, ql1);
    }

    float m0 = -1e30f, m1 = -1e30f, m2 = -1e30f, m3 = -1e30f;
    float l0 = 0.f, l1 = 0.f, l2 = 0.f, l3 = 0.f;
    f32x4 oacc[4];
#pragma unroll
    for (int i = 0; i < 4; ++i) oacc[i] = (f32x4){0.f, 0.f, 0.f, 0.f};

    // ---- exactly ONE 128-key chunk per wave (uniform critical path) ----
    const int kb = seg * 512 + w * 128;
    if (kb <= q_max) {
        const int rem  = q_max - kb;
        const int nsub = min(8, (rem >> 4) + 1);
        const int nchain = (nsub + 1) >> 1;
        f32x4 sacc[8];

        // ---- QK^T: 8 subtiles in pairs; contiguous 1KB frag loads ----
#pragma unroll
        for (int gp = 0; gp < 4; ++gp) {
            const int stA = 2 * gp, stB = stA + 1;
            if (stA < nsub) {
                const unsigned short* pA = KfL + (((size_t)((kb >> 4) + stA)) << 11);
                short8 khA0 = ld8(pA),        khA1 = ld8(pA + 512);
                short8 klA0 = ld8(pA + 1024), klA1 = ld8(pA + 1536);
                const bool okB = (stB < nsub);
                const unsigned short* pB = KfL + (((size_t)((kb >> 4) + stB)) << 11);
                short8 khB0, khB1, klB0, klB1;
                if (okB) {
                    khB0 = ld8(pB);        khB1 = ld8(pB + 512);
                    klB0 = ld8(pB + 1024); klB1 = ld8(pB + 1536);
                }
                f32x4 accA = (f32x4){0.f, 0.f, 0.f, 0.f};
                accA = MFMA(qh0, khA0, accA);
                accA = MFMA(qh1, khA1, accA);
                accA = MFMA(qh0, klA0, accA);
                accA = MFMA(qh1, klA1, accA);
                accA = MFMA(ql0, khA0, accA);
                accA = MFMA(ql1, khA1, accA);
                sacc[stA] = accA;
                if (okB) {
                    f32x4 accB = (f32x4){0.f, 0.f, 0.f, 0.f};
                    accB = MFMA(qh0, khB0, accB);
                    accB = MFMA(qh1, khB1, accB);
                    accB = MFMA(qh0, klB0, accB);
                    accB = MFMA(qh1, klB1, accB);
                    accB = MFMA(ql0, khB0, accB);
                    accB = MFMA(ql1, khB1, accB);
                    sacc[stB] = accB;
                } else {
                    sacc[stB] = (f32x4){-1e30f, -1e30f, -1e30f, -1e30f};
                }
            } else {
                sacc[stA] = (f32x4){-1e30f, -1e30f, -1e30f, -1e30f};
                sacc[stB] = (f32x4){-1e30f, -1e30f, -1e30f, -1e30f};
            }
        }

        // ---- causal mask (only the final segment can overlap) ----
        if (kb + 127 > q0) {
#pragma unroll
            for (int st = 0; st < 8; ++st) {
                if (st < nsub) {
                    const int key = kb + st * 16 + n16;
#pragma unroll
                    for (int r = 0; r < 4; ++r)
                        if (key > q0 + quad * 4 + r) sacc[st][r] = -1e30f;
                }
            }
        }

        // ---- softmax over this 128-key chunk (DPP reductions) ----
        float mt0 = sacc[0][0], mt1 = sacc[0][1], mt2 = sacc[0][2], mt3 = sacc[0][3];
#pragma unroll
        for (int st = 1; st < 8; ++st) {
            mt0 = fmaxf(mt0, sacc[st][0]);
            mt1 = fmaxf(mt1, sacc[st][1]);
            mt2 = fmaxf(mt2, sacc[st][2]);
            mt3 = fmaxf(mt3, sacc[st][3]);
        }
        mt0 = dpp_max16(mt0); mt1 = dpp_max16(mt1);
        mt2 = dpp_max16(mt2); mt3 = dpp_max16(mt3);
        const float mn0 = fmaxf(m0, mt0), mn1 = fmaxf(m1, mt1);
        const float mn2 = fmaxf(m2, mt2), mn3 = fmaxf(m3, mt3);
        const float a0 = __expf(m0 - mn0), a1 = __expf(m1 - mn1);
        const float a2 = __expf(m2 - mn2), a3 = __expf(m3 - mn3);
        m0 = mn0; m1 = mn1; m2 = mn2; m3 = mn3;

        float ps0 = 0.f, ps1 = 0.f, ps2 = 0.f, ps3 = 0.f;
        const int stmax = 2 * nchain;
#pragma unroll
        for (int st = 0; st < 8; ++st) {
            if (st < stmax) {
                float p0 = 0.f, p1 = 0.f, p2 = 0.f, p3 = 0.f;
                if (st < nsub) {
                    p0 = __expf(sacc[st][0] - mn0);
                    p1 = __expf(sacc[st][1] - mn1);
                    p2 = __expf(sacc[st][2] - mn2);
                    p3 = __expf(sacc[st][3] - mn3);
                    ps0 += p0; ps1 += p1; ps2 += p2; ps3 += p3;
                }
                const int col = st * 16 + n16;
                const unsigned r01 = cvt_pk_bf16(p0, p1);
                const unsigned r23 = cvt_pk_bf16(p2, p3);
                sPw[(quad * 4 + 0) * 136 + col] = (unsigned short)r01;
                sPw[(quad * 4 + 1) * 136 + col] = (unsigned short)(r01 >> 16);
                sPw[(quad * 4 + 2) * 136 + col] = (unsigned short)r23;
                sPw[(quad * 4 + 3) * 136 + col] = (unsigned short)(r23 >> 16);
            }
        }
        ps0 = dpp_sum16(ps0); ps1 = dpp_sum16(ps1);
        ps2 = dpp_sum16(ps2); ps3 = dpp_sum16(ps3);
        l0 = l0 * a0 + ps0; l1 = l1 * a1 + ps1;
        l2 = l2 * a2 + ps2; l3 = l3 * a3 + ps3;
#pragma unroll
        for (int nt = 0; nt < 4; ++nt) {
            oacc[nt][0] *= a0; oacc[nt][1] *= a1;
            oacc[nt][2] *= a2; oacc[nt][3] *= a3;
        }

        // ---- PV: P from same-wave LDS; V via dense fragment-major loads ----
#pragma unroll
        for (int ch = 0; ch < 4; ++ch) {
            if (ch < nchain) {
                short8 pa = ld8(&sPw[n16 * 136 + ch * 32 + quad * 8]);
                const size_t cbase =
                    (((size_t)(b * 64 + (kb >> 5) + ch)) * 4) << 9;
#pragma unroll
                for (int nt = 0; nt < 4; ++nt) {
                    short8 vv = ld8(Vf + cbase + (nt << 9) + lane * 8);
                    oacc[nt] = MFMA(pa, vv, oacc[nt]);
                }
            }
        }
    }

    // ---- in-block combine of 4 waves (sO overlays sP) ----
#pragma unroll
    for (int nt = 0; nt < 4; ++nt)
#pragma unroll
        for (int r = 0; r < 4; ++r)
            sOw[(quad * 4 + r) * 68 + nt * 16 + n16] = oacc[nt][r];
    if (n16 == 0) {
        sMl[w][quad * 4 + 0][0] = m0; sMl[w][quad * 4 + 0][1] = l0;
        sMl[w][quad * 4 + 1][0] = m1; sMl[w][quad * 4 + 1][1] = l1;
        sMl[w][quad * 4 + 2][0] = m2; sMl[w][quad * 4 + 2][1] = l2;
        sMl[w][quad * 4 + 3][0] = m3; sMl[w][quad * 4 + 3][1] = l3;
    }
    __syncthreads();

    const int row  = t >> 4;
    const int col4 = (t & 15) * 4;
    float M = fmaxf(fmaxf(sMl[0][row][0], sMl[1][row][0]),
                    fmaxf(sMl[2][row][0], sMl[3][row][0]));
    float L = 0.f;
    float ox = 0.f, oy = 0.f, oz = 0.f, ow = 0.f;
#pragma unroll
    for (int wv = 0; wv < 4; ++wv) {
        const float ew = __expf(sMl[wv][row][0] - M);
        L += ew * sMl[wv][row][1];
        const float* op = (const float*)scratch[wv] + row * 68 + col4;
        ox += ew * op[0]; oy += ew * op[1]; oz += ew * op[2]; ow += ew * op[3];
    }

    // ---- write UNNORMALIZED partial (segment frame M) ----
    const int pb = ((b << 7) + qt) * 4 + seg;
    float* po = Po + (((size_t)pb * 16 + row) << 6) + col4;
    *(float4*)po = make_float4(ox, oy, oz, ow);
    if (col4 == 0) {
        Pml[pb * 32 + row * 2 + 0] = M;
        Pml[pb * 32 + row * 2 + 1] = L;
    }
}

// ---- cross-segment combine + normalize: 1024 blocks x 256 threads ----
__global__ __launch_bounds__(256) void combine(
    const float* __restrict__ Po, const float* __restrict__ Pml,
    float* __restrict__ O)
{
    const int bid = blockIdx.x;             // 0..1023
    const int b   = bid & (BATCH - 1);
    const int qt  = bid >> 3;               // 0..127
    const int nseg = (qt >> 5) + 1;

    const int t    = threadIdx.x;
    const int row  = t >> 4;
    const int col4 = (t & 15) * 4;
    const int pb0  = ((b << 7) + qt) * 4;

    float M = Pml[pb0 * 32 + row * 2];
#pragma unroll 4
    for (int s = 1; s < nseg; ++s)
        M = fmaxf(M, Pml[(pb0 + s) * 32 + row * 2]);

    float L = 0.f;
    float ox = 0.f, oy = 0.f, oz = 0.f, ow = 0.f;
#pragma unroll 4
    for (int s = 0; s < nseg; ++s) {
        const float Ms = Pml[(pb0 + s) * 32 + row * 2 + 0];
        const float Ls = Pml[(pb0 + s) * 32 + row * 2 + 1];
        const float ew = __expf(Ms - M);
        L += ew * Ls;
        const float* po = Po + (((size_t)(pb0 + s) * 16 + row) << 6) + col4;
        float4 v = *(const float4*)po;
        ox += ew * v.x; oy += ew * v.y; oz += ew * v.z; ow += ew * v.w;
    }
    const float inv = 1.0f / L;
    float* dst = O + ((size_t)(b * SEQ + qt * 16 + row)) * DIM + col4;
    *(float4*)dst = make_float4(ox * inv, oy * inv, oz * inv, ow * inv);
}

extern "C" void kernel_launch(void* const* d_in, const int* in_sizes, int n_in,
                              void* d_out, int out_size, void* d_ws, size_t ws_size,
                              hipStream_t stream) {
    const float* q = (const float*)d_in[0];
    const float* k = (const float*)d_in[1];
    const float* v = (const float*)d_in[2];
    float* out = (float*)d_out;

    unsigned short* Kf = (unsigned short*)d_ws;   // 4 MB fragment-major hi/lo
    unsigned short* Vf = Kf + 2 * NEL;            // 2 MB fragment-major V
    float* Po  = (float*)(Vf + NEL);              // 4096 x 16 x 64 f32 (16.8 MB)
    float* Pml = Po + (size_t)4096 * 16 * 64;     // 4096 x 16 x 2 f32 (0.5 MB)

    prep<<<dim3(512 + 256), dim3(256), 0, stream>>>(k, v, Kf, Vf);
    attn_main<<<dim3(2560), dim3(256), 0, stream>>>(q, Kf, Vf, Po, Pml);
    combine<<<dim3(1024), dim3(256), 0, stream>>>(Po, Pml, out);
}

// Round 10
// 90.780 us; speedup vs baseline: 1.2064x; 1.0871x over previous
//
#include <hip/hip_runtime.h>

// Causal attention, fp32 in/out, B=8 S=2048 D=64, NO 1/sqrt(d) scaling.
// R25 = FINAL REVERT to R22/R19 (session best: 90.27us total).
//  - R24 post-mortem: uniform 2D decomposition regressed (98.68): the
//    tail never existed (R18's pair-blocks were already uniform and
//    scored the same 90.x); R24 paid ~8us of real overhead (3rd
//    dispatch, 2.5x Q prologue, 34MB partial round-trip).
//  - Session ledger (R23 probe-derived): ~43us ws-poison fill (268MB @
//    6.2TB/s = 78% HBM peak - the fill is at ITS roofline, not ours),
//    ~6us prep, ~37us attn_main, ~4us launch gaps.
//  - attn_main theories tested: occupancy x2 null (R17,R19); traffic
//    x0.5 regressed (R20,R21); VALU count null (R22); tail null (R24,
//    R18~R19 cross-check). Only load SHAPE paid (R18: 16-segment K
//    gather -> contiguous 1KB bursts, -40%). Remaining regime:
//    dependency-latency with all pipes <40% busy; no counter-supported
//    lever remains.
//  - This kernel: bit-identical math to R19 (absmax exactly 0.03125),
//    fragment-major Kf/Vf, 1024 one-tile blocks, snake-balanced,
//    cvt_pk P-conversion (neutral but fewer ops).
// Fragment layouts (verified R2):
//   A[m][k]: m=lane&15, k=quad*8+j | B[k][n]: n=lane&15, k=quad*8+j
//   C/D:     col=lane&15, row=quad*4+reg
// Vf layout: chunk c(32 keys), dim-group nt: lane l holds
//   V[b][c*32+(l>>4)*8+j][nt*16+(l&15)], j=0..7 (16B, consecutive by lane).
// Kf layout: subtile S(16 keys), frag f: lane l holds 16B at
//   Kf + (b*128+S)*2048 + f*512 + l*8   (elements, 2B each)
//   f0/f1 = hi dims 0-31 / 32-63, f2/f3 = lo dims 0-31 / 32-63.

#define BATCH 8
#define SEQ 2048
#define DIM 64
#define NEL (BATCH * SEQ * DIM)

typedef __attribute__((ext_vector_type(8))) short short8;
typedef __attribute__((ext_vector_type(4))) float f32x4;

#define MFMA(a, b, c) __builtin_amdgcn_mfma_f32_16x16x32_bf16(a, b, c, 0, 0, 0)

__device__ __forceinline__ unsigned short f2bf(float x) {   // RNE
    unsigned u = __float_as_uint(x);
    unsigned r = u + 0x7fffu + ((u >> 16) & 1u);
    return (unsigned short)(r >> 16);
}
__device__ __forceinline__ float bf2f(unsigned short h) {
    return __uint_as_float(((unsigned)h) << 16);
}
// packed f32x2 -> bf16x2, RNE; lo 16 bits from a, hi 16 bits from b.
__device__ __forceinline__ unsigned cvt_pk_bf16(float a, float b) {
    unsigned r;
    asm("v_cvt_pk_bf16_f32 %0, %1, %2" : "=v"(r) : "v"(a), "v"(b));
    return r;
}
__device__ __forceinline__ short8 ld8(const unsigned short* p) {
    return *(const short8*)p;
}
// truncation hi/lo split (R14-verified): hi = upper16(x); lo = trunc16(x-hi).
__device__ __forceinline__ void splitA(float4 a, float4 b, short8& h8, short8& l8) {
    float v[8] = {a.x, a.y, a.z, a.w, b.x, b.y, b.z, b.w};
#pragma unroll
    for (int i = 0; i < 8; ++i) {
        unsigned u  = __float_as_uint(v[i]);
        unsigned hu = u & 0xffff0000u;
        h8[i] = (short)(hu >> 16);
        float lf = v[i] - __uint_as_float(hu);
        l8[i] = (short)(__float_as_uint(lf) >> 16);
    }
}

__device__ __forceinline__ float dpp_max16(float x) {
    float o;
    o = __int_as_float(__builtin_amdgcn_update_dpp(0, __float_as_int(x), 0xB1, 0xF, 0xF, true));
    x = fmaxf(x, o);
    o = __int_as_float(__builtin_amdgcn_update_dpp(0, __float_as_int(x), 0x4E, 0xF, 0xF, true));
    x = fmaxf(x, o);
    o = __int_as_float(__builtin_amdgcn_update_dpp(0, __float_as_int(x), 0x141, 0xF, 0xF, true));
    x = fmaxf(x, o);
    o = __int_as_float(__builtin_amdgcn_update_dpp(0, __float_as_int(x), 0x140, 0xF, 0xF, true));
    return fmaxf(x, o);
}
__device__ __forceinline__ float dpp_sum16(float x) {
    float o;
    o = __int_as_float(__builtin_amdgcn_update_dpp(0, __float_as_int(x), 0xB1, 0xF, 0xF, true));
    x += o;
    o = __int_as_float(__builtin_amdgcn_update_dpp(0, __float_as_int(x), 0x4E, 0xF, 0xF, true));
    x += o;
    o = __int_as_float(__builtin_amdgcn_update_dpp(0, __float_as_int(x), 0x141, 0xF, 0xF, true));
    x += o;
    o = __int_as_float(__builtin_amdgcn_update_dpp(0, __float_as_int(x), 0x140, 0xF, 0xF, true));
    return x + o;
}

// ---- pre-pass: K fragment-major hi/lo (blk<512) + V fragment-major ----
__global__ __launch_bounds__(256) void prep(
    const float* __restrict__ K, const float* __restrict__ V,
    unsigned short* __restrict__ Kf, unsigned short* __restrict__ Vf)
{
    __shared__ unsigned short sT[64][72];   // [dim][key] for one 64-key tile
    const int blk = blockIdx.x;
    const int t = threadIdx.x;

    if (blk < 512) {
        // one thread = one (subtile, dim-half, lane) chunk: 8 fp32 -> hi8+lo8
        const int g  = blk * 256 + t;       // 0..131071
        const int l  = g & 63;
        const int h  = (g >> 6) & 1;
        const int Sg = g >> 7;              // b*128 + S, 0..1023
        const int b  = Sg >> 7;
        const int S  = Sg & 127;
        const int key = S * 16 + (l & 15);
        const float* src = K + ((size_t)(b * SEQ + key)) * DIM + h * 32 + (l >> 4) * 8;
        float4 a = *(const float4*)src;
        float4 c = *(const float4*)(src + 4);
        float v[8] = {a.x, a.y, a.z, a.w, c.x, c.y, c.z, c.w};
        short8 h8, l8;
#pragma unroll
        for (int i = 0; i < 8; ++i) {
            unsigned short hh = f2bf(v[i]);
            h8[i] = (short)hh;
            l8[i] = (short)f2bf(v[i] - bf2f(hh));
        }
        unsigned short* dst = Kf + (((size_t)Sg) << 11) + (h << 9) + l * 8;
        *(short8*)dst = h8;                  // frag f = h   (hi)
        *(short8*)(dst + 1024) = l8;         // frag f = 2+h (lo)
        return;
    }

    const int tile = blk - 512;             // 8 batches * 32 tiles of 64 keys
    const int b = tile >> 5;
    const int s0 = (tile & 31) * 64;
    const int srow = t >> 4;
    const int d4   = (t & 15) * 4;
#pragma unroll
    for (int i = 0; i < 4; ++i) {
        const int row = srow + i * 16;
        float4 v = *(const float4*)(V + ((size_t)(b * SEQ + s0 + row)) * DIM + d4);
        sT[d4 + 0][row] = f2bf(v.x);
        sT[d4 + 1][row] = f2bf(v.y);
        sT[d4 + 2][row] = f2bf(v.z);
        sT[d4 + 3][row] = f2bf(v.w);
    }
    __syncthreads();
#pragma unroll
    for (int i = 0; i < 2; ++i) {
        const int fid = t + i * 256;
        const int cc  = fid >> 8;
        const int nt  = (fid >> 6) & 3;
        const int l   = fid & 63;
        const int key = cc * 32 + (l >> 4) * 8;
        const int dim = nt * 16 + (l & 15);
        const int c   = (s0 >> 5) + cc;
        unsigned short* dst =
            Vf + ((((size_t)(b * 64 + c)) * 4 + nt) << 9) + l * 8;
        *(float4*)dst = *(const float4*)&sT[dim][key];
    }
}

// ---- main: 1024 blocks x 256 threads (4 waves), ONE q-tile per block ----
__global__ __launch_bounds__(256) void attn_main(
    const float* __restrict__ Q,
    const unsigned short* __restrict__ Kf,
    const unsigned short* __restrict__ Vf, float* __restrict__ O)
{
    // per-wave union scratch: sP (ushort[16][136]) == sO (float[16][68]) = 4352B
    __shared__ __align__(16) char scratch[4][4352];
    __shared__ float sMl[4][16][2];

    const int bid  = blockIdx.x;
    // snake mapping: per-CU work sum constant under striped assignment
    const int g    = bid >> 8;              // grid quarter 0..3
    const int idx  = bid & 255;
    const int b    = idx & (BATCH - 1);
    const int tl   = idx >> 3;              // 0..31
    const int qt   = (g & 1) ? (g * 32 + 31 - tl) : (g * 32 + tl);

    const int t    = threadIdx.x;
    const int w    = t >> 6;
    const int lane = t & 63;
    const int quad = lane >> 4;
    const int n16  = lane & 15;
    const int boff = b * SEQ;

    unsigned short* sPw = (unsigned short*)scratch[w];   // [16][136]
    float*          sOw = (float*)scratch[w];            // [16][68]

    // base of this batch's Kf region, plus this lane's 16B slot
    const unsigned short* KfL = Kf + (((size_t)(b * 128)) << 11) + lane * 8;

    const int q0 = qt * 16;
    const int q_max = q0 + 15;

    // ---- Q fragments: inline fp32 -> hi/lo truncation split ----
    short8 qh0, ql0, qh1, ql1;
    {
        const float* qb = Q + ((size_t)(boff + q0 + n16)) * DIM + quad * 8;
        splitA(*(const float4*)(qb),      *(const float4*)(qb + 4),  qh0, ql0);
        splitA(*(const float4*)(qb + 32), *(const float4*)(qb + 36), qh1, ql1);
    }

    float m0 = -1e30f, m1 = -1e30f, m2 = -1e30f, m3 = -1e30f;
    float l0 = 0.f, l1 = 0.f, l2 = 0.f, l3 = 0.f;
    f32x4 oacc[4];
#pragma unroll
    for (int i = 0; i < 4; ++i) oacc[i] = (f32x4){0.f, 0.f, 0.f, 0.f};

    for (int kb = w * 128; kb <= q_max; kb += 512) {
        const int rem  = q_max - kb;
        const int nsub = min(8, (rem >> 4) + 1);
        const int nchain = (nsub + 1) >> 1;
        f32x4 sacc[8];

        // ---- QK^T: 8 subtiles in pairs; contiguous 1KB frag loads ----
#pragma unroll
        for (int gp = 0; gp < 4; ++gp) {
            const int stA = 2 * gp, stB = stA + 1;
            if (stA < nsub) {
                const unsigned short* pA = KfL + (((size_t)((kb >> 4) + stA)) << 11);
                short8 khA0 = ld8(pA),        khA1 = ld8(pA + 512);
                short8 klA0 = ld8(pA + 1024), klA1 = ld8(pA + 1536);
                const bool okB = (stB < nsub);
                const unsigned short* pB = KfL + (((size_t)((kb >> 4) + stB)) << 11);
                short8 khB0, khB1, klB0, klB1;
                if (okB) {
                    khB0 = ld8(pB);        khB1 = ld8(pB + 512);
                    klB0 = ld8(pB + 1024); klB1 = ld8(pB + 1536);
                }
                f32x4 accA = (f32x4){0.f, 0.f, 0.f, 0.f};
                accA = MFMA(qh0, khA0, accA);
                accA = MFMA(qh1, khA1, accA);
                accA = MFMA(qh0, klA0, accA);
                accA = MFMA(qh1, klA1, accA);
                accA = MFMA(ql0, khA0, accA);
                accA = MFMA(ql1, khA1, accA);
                sacc[stA] = accA;
                if (okB) {
                    f32x4 accB = (f32x4){0.f, 0.f, 0.f, 0.f};
                    accB = MFMA(qh0, khB0, accB);
                    accB = MFMA(qh1, khB1, accB);
                    accB = MFMA(qh0, klB0, accB);
                    accB = MFMA(qh1, klB1, accB);
                    accB = MFMA(ql0, khB0, accB);
                    accB = MFMA(ql1, khB1, accB);
                    sacc[stB] = accB;
                } else {
                    sacc[stB] = (f32x4){-1e30f, -1e30f, -1e30f, -1e30f};
                }
            } else {
                sacc[stA] = (f32x4){-1e30f, -1e30f, -1e30f, -1e30f};
                sacc[stB] = (f32x4){-1e30f, -1e30f, -1e30f, -1e30f};
            }
        }

        // ---- causal mask: any chunk overlapping any query row ----
        if (kb + 127 > q0) {
#pragma unroll
            for (int st = 0; st < 8; ++st) {
                if (st < nsub) {
                    const int key = kb + st * 16 + n16;
#pragma unroll
                    for (int r = 0; r < 4; ++r)
                        if (key > q0 + quad * 4 + r) sacc[st][r] = -1e30f;
                }
            }
        }

        // ---- online softmax over 128 keys (DPP reductions) ----
        float mt0 = sacc[0][0], mt1 = sacc[0][1], mt2 = sacc[0][2], mt3 = sacc[0][3];
#pragma unroll
        for (int st = 1; st < 8; ++st) {
            mt0 = fmaxf(mt0, sacc[st][0]);
            mt1 = fmaxf(mt1, sacc[st][1]);
            mt2 = fmaxf(mt2, sacc[st][2]);
            mt3 = fmaxf(mt3, sacc[st][3]);
        }
        mt0 = dpp_max16(mt0); mt1 = dpp_max16(mt1);
        mt2 = dpp_max16(mt2); mt3 = dpp_max16(mt3);
        const float mn0 = fmaxf(m0, mt0), mn1 = fmaxf(m1, mt1);
        const float mn2 = fmaxf(m2, mt2), mn3 = fmaxf(m3, mt3);
        const float a0 = __expf(m0 - mn0), a1 = __expf(m1 - mn1);
        const float a2 = __expf(m2 - mn2), a3 = __expf(m3 - mn3);
        m0 = mn0; m1 = mn1; m2 = mn2; m3 = mn3;

        float ps0 = 0.f, ps1 = 0.f, ps2 = 0.f, ps3 = 0.f;
        const int stmax = 2 * nchain;
#pragma unroll
        for (int st = 0; st < 8; ++st) {
            if (st < stmax) {
                float p0 = 0.f, p1 = 0.f, p2 = 0.f, p3 = 0.f;
                if (st < nsub) {
                    p0 = __expf(sacc[st][0] - mn0);
                    p1 = __expf(sacc[st][1] - mn1);
                    p2 = __expf(sacc[st][2] - mn2);
                    p3 = __expf(sacc[st][3] - mn3);
                    ps0 += p0; ps1 += p1; ps2 += p2; ps3 += p3;
                }
                const int col = st * 16 + n16;
                // packed RNE convert: 2 cvt_pk + 2 shifts replace 4x ~4-op f2bf
                const unsigned r01 = cvt_pk_bf16(p0, p1);
                const unsigned r23 = cvt_pk_bf16(p2, p3);
                sPw[(quad * 4 + 0) * 136 + col] = (unsigned short)r01;
                sPw[(quad * 4 + 1) * 136 + col] = (unsigned short)(r01 >> 16);
                sPw[(quad * 4 + 2) * 136 + col] = (unsigned short)r23;
                sPw[(quad * 4 + 3) * 136 + col] = (unsigned short)(r23 >> 16);
            }
        }
        ps0 = dpp_sum16(ps0); ps1 = dpp_sum16(ps1);
        ps2 = dpp_sum16(ps2); ps3 = dpp_sum16(ps3);
        l0 = l0 * a0 + ps0; l1 = l1 * a1 + ps1;
        l2 = l2 * a2 + ps2; l3 = l3 * a3 + ps3;
#pragma unroll
        for (int nt = 0; nt < 4; ++nt) {
            oacc[nt][0] *= a0; oacc[nt][1] *= a1;
            oacc[nt][2] *= a2; oacc[nt][3] *= a3;
        }

        // ---- PV: P from same-wave LDS; V via dense fragment-major loads ----
#pragma unroll
        for (int ch = 0; ch < 4; ++ch) {
            if (ch < nchain) {
                short8 pa = ld8(&sPw[n16 * 136 + ch * 32 + quad * 8]);
                const size_t cbase =
                    (((size_t)(b * 64 + (kb >> 5) + ch)) * 4) << 9;
#pragma unroll
                for (int nt = 0; nt < 4; ++nt) {
                    short8 vv = ld8(Vf + cbase + (nt << 9) + lane * 8);
                    oacc[nt] = MFMA(pa, vv, oacc[nt]);
                }
            }
        }
    }

    // ---- flash-combine the 4 waves' partials (sO overlays sP) ----
#pragma unroll
    for (int nt = 0; nt < 4; ++nt)
#pragma unroll
        for (int r = 0; r < 4; ++r)
            sOw[(quad * 4 + r) * 68 + nt * 16 + n16] = oacc[nt][r];
    if (n16 == 0) {
        sMl[w][quad * 4 + 0][0] = m0; sMl[w][quad * 4 + 0][1] = l0;
        sMl[w][quad * 4 + 1][0] = m1; sMl[w][quad * 4 + 1][1] = l1;
        sMl[w][quad * 4 + 2][0] = m2; sMl[w][quad * 4 + 2][1] = l2;
        sMl[w][quad * 4 + 3][0] = m3; sMl[w][quad * 4 + 3][1] = l3;
    }
    __syncthreads();

    const int row  = t >> 4;
    const int col4 = (t & 15) * 4;
    float M = fmaxf(fmaxf(sMl[0][row][0], sMl[1][row][0]),
                    fmaxf(sMl[2][row][0], sMl[3][row][0]));
    float L = 0.f;
    float ox = 0.f, oy = 0.f, oz = 0.f, ow = 0.f;
#pragma unroll
    for (int wv = 0; wv < 4; ++wv) {
        const float ew = __expf(sMl[wv][row][0] - M);
        L += ew * sMl[wv][row][1];
        const float* op = (const float*)scratch[wv] + row * 68 + col4;
        ox += ew * op[0]; oy += ew * op[1]; oz += ew * op[2]; ow += ew * op[3];
    }
    const float inv = 1.0f / L;
    float4 res = make_float4(ox * inv, oy * inv, oz * inv, ow * inv);
    *(float4*)(O + ((size_t)(boff + q0 + row)) * DIM + col4) = res;
}

extern "C" void kernel_launch(void* const* d_in, const int* in_sizes, int n_in,
                              void* d_out, int out_size, void* d_ws, size_t ws_size,
                              hipStream_t stream) {
    const float* q = (const float*)d_in[0];
    const float* k = (const float*)d_in[1];
    const float* v = (const float*)d_in[2];
    float* out = (float*)d_out;

    unsigned short* Kf = (unsigned short*)d_ws;   // 4 MB fragment-major hi/lo
    unsigned short* Vf = Kf + 2 * NEL;            // 2 MB fragment-major V

    prep<<<dim3(512 + 256), dim3(256), 0, stream>>>(k, v, Kf, Vf);
    attn_main<<<dim3(1024), dim3(256), 0, stream>>>(q, Kf, Vf, out);
}